// Round 3
// baseline (33880.911 us; speedup 1.0000x reference)
//
#include <hip/hip_runtime.h>
#include <hip/hip_bf16.h>

// LSTM classifier: emb gather -> input GEMM (fp16 MFMA) -> persistent
// recurrence kernel (64 WGs x 512 thr; all cross-WG data via sc1/LLC,
// zero fences, W_hh in registers) -> logits.
//
// Workspace layout (bytes):
//   emb16   @ 0          : 50257*1024*2 = 102,926,336
//   wih16   @ 102926336  : 4096*1024*2  =   8,388,608
//   wr16    @ 111314944  : 4096*1024*2  =   8,388,608   (W_hh reordered, fp16)
//   bias    @ 119703552  : 4096*4       =      16,384   (b_ih + b_hh, f32)
//   xg      @ 119719936  : 65536*4096*2 = 536,870,912   (x_gates fp16, [t][b][R'])
//   h_all   @ 656590848  : 2049*32*1024*2 = 134,283,264 (h per step, fp16)
//   flags   @ 790874112  : 64*32*4      =       8,192   (per-WG step flags)
//   total: 790,882,304

typedef _Float16 f16;
typedef _Float16 f16x8 __attribute__((ext_vector_type(8)));
typedef _Float16 f16x4 __attribute__((ext_vector_type(4)));
typedef float    f32x4 __attribute__((ext_vector_type(4)));
typedef unsigned long long u64;

#define B_    32
#define T_    2048
#define W_    1024
#define H_    1024
#define G4_   4096

__device__ __forceinline__ void gl_lds16(const void* g, void* l) {
  __builtin_amdgcn_global_load_lds(
      (const __attribute__((address_space(1))) void*)g,
      (__attribute__((address_space(3))) void*)l, 16, 0, 0);
}

// agent-scope (sc1 / LLC-coherent) helpers — bypass non-coherent XCD L2s
__device__ __forceinline__ u64 llc_ld64(const void* p) {
  return __hip_atomic_load((const u64*)p, __ATOMIC_RELAXED, __HIP_MEMORY_SCOPE_AGENT);
}
__device__ __forceinline__ void llc_st16(void* p, unsigned short v) {
  __hip_atomic_store((unsigned short*)p, v, __ATOMIC_RELAXED, __HIP_MEMORY_SCOPE_AGENT);
}

// ---------------- conversions ----------------

__global__ void k_cvt_f16(const float* __restrict__ in, f16* __restrict__ out, long n4) {
  long i = (long)blockIdx.x * blockDim.x + threadIdx.x;
  if (i >= n4) return;
  float4 v = ((const float4*)in)[i];
  f16x4 o; o[0] = (f16)v.x; o[1] = (f16)v.y; o[2] = (f16)v.z; o[3] = (f16)v.w;
  *(f16x4*)(out + i * 4) = o;
}

// W_hh row (q*1024 + j) -> wr16 row R' = (j>>4)*64 + (j&15)*4 + q; fp16.
// => WG wid owns contiguous rows [wid*64, wid*64+64) = h-dims [wid*16, +16).
__global__ void k_whh_reorder(const float* __restrict__ whh, f16* __restrict__ wr) {
  unsigned i = blockIdx.x * blockDim.x + threadIdx.x;   // one thread per 8 elems
  unsigned e0 = i * 8;
  unsigned R = e0 >> 10, k = e0 & 1023;
  unsigned q = R >> 10, j = R & 1023;
  unsigned outR = ((j >> 4) << 6) + ((j & 15) << 2) + q;
  float4 v0 = ((const float4*)whh)[e0 / 4];
  float4 v1 = ((const float4*)whh)[e0 / 4 + 1];
  f16x8 o;
  o[0] = (f16)v0.x; o[1] = (f16)v0.y; o[2] = (f16)v0.z; o[3] = (f16)v0.w;
  o[4] = (f16)v1.x; o[5] = (f16)v1.y; o[6] = (f16)v1.z; o[7] = (f16)v1.w;
  *(f16x8*)&wr[((size_t)outR << 10) + k] = o;
}

__global__ void k_bias(const float* __restrict__ bi, const float* __restrict__ bh,
                       float* __restrict__ bo) {
  unsigned i = blockIdx.x * blockDim.x + threadIdx.x;
  if (i < G4_) bo[i] = bi[i] + bh[i];
}

// ---------------- input GEMM: xg[m][R'(n)] = emb[seq] @ W_ih^T + bias ----------------
// m = t*32 + b (so xg layout is [t][b][R']); 128x128 tile, BK=64, 4 waves.

__global__ __launch_bounds__(256) void k_gemm_xg(
    const int* __restrict__ seq, const f16* __restrict__ emb16,
    const f16* __restrict__ wih16, const float* __restrict__ bias,
    f16* __restrict__ xg) {
  __shared__ f16 As[128 * 64];
  __shared__ f16 Bs[128 * 64];
  const unsigned tid = threadIdx.x;
  const unsigned w = tid >> 6, lane = tid & 63;
  const unsigned bid = blockIdx.x;
  const unsigned tn = bid & 31, tm = bid >> 5;
  const unsigned wm = (w >> 1) * 64, wn = (w & 1) * 64;

  f32x4 zero = {0.f, 0.f, 0.f, 0.f};
  f32x4 acc[4][4];
#pragma unroll
  for (int i = 0; i < 4; ++i)
#pragma unroll
    for (int j = 0; j < 4; ++j) acc[i][j] = zero;

  for (unsigned kk = 0; kk < 16; ++kk) {
    const unsigned k0 = kk * 64;
#pragma unroll
    for (unsigned c = 0; c < 4; ++c) {
      unsigned idx = c * 256 + tid;
      unsigned row = idx >> 3, ch = idx & 7;
      unsigned chs = ch ^ (row & 7);
      unsigned m = tm * 128 + row;
      unsigned t = m >> 5, b = m & 31;
      int e = seq[b * 2048 + t];
      const f16* src = emb16 + ((size_t)e << 10) + k0 + chs * 8;
      gl_lds16(src, (char*)As + c * 4096 + w * 1024);
    }
#pragma unroll
    for (unsigned c = 0; c < 4; ++c) {
      unsigned idx = c * 256 + tid;
      unsigned row = idx >> 3, ch = idx & 7;
      unsigned chs = ch ^ (row & 7);
      unsigned n = tn * 128 + row;
      const f16* src = wih16 + ((size_t)n << 10) + k0 + chs * 8;
      gl_lds16(src, (char*)Bs + c * 4096 + w * 1024);
    }
    __syncthreads();
#pragma unroll
    for (unsigned ks = 0; ks < 2; ++ks) {
      f16x8 af[4], bf[4];
      unsigned kc = ks * 4 + (lane >> 4);
#pragma unroll
      for (unsigned fm = 0; fm < 4; ++fm) {
        unsigned r = wm + fm * 16 + (lane & 15);
        af[fm] = *(const f16x8*)&As[r * 64 + ((kc ^ (r & 7)) << 3)];
      }
#pragma unroll
      for (unsigned fn = 0; fn < 4; ++fn) {
        unsigned r = wn + fn * 16 + (lane & 15);
        bf[fn] = *(const f16x8*)&Bs[r * 64 + ((kc ^ (r & 7)) << 3)];
      }
#pragma unroll
      for (unsigned fm = 0; fm < 4; ++fm)
#pragma unroll
        for (unsigned fn = 0; fn < 4; ++fn)
          acc[fm][fn] = __builtin_amdgcn_mfma_f32_16x16x32_f16(af[fm], bf[fn], acc[fm][fn], 0, 0, 0);
    }
    __syncthreads();
  }
  // epilogue: + bias, fp16 store into gate-interleaved layout R'
#pragma unroll
  for (unsigned fn = 0; fn < 4; ++fn) {
    unsigned n = tn * 128 + wn + fn * 16 + (lane & 15);
    unsigned q = n >> 10, j = n & 1023;
    unsigned Rp = ((j >> 4) << 6) + ((j & 15) << 2) + q;
    float bv = bias[n];
#pragma unroll
    for (unsigned fm = 0; fm < 4; ++fm) {
#pragma unroll
      for (unsigned rg = 0; rg < 4; ++rg) {
        unsigned m = tm * 128 + wm + fm * 16 + (lane >> 4) * 4 + rg;
        xg[(size_t)m * G4_ + Rp] = (f16)(acc[fm][fn][rg] + bv);
      }
    }
  }
}

// ---------------- persistent LSTM recurrence ----------------
// 64 WGs x 512 threads (8 waves = 2 M-tiles x 4 N-tiles). WG wid owns h-dims
// [wid*16, wid*16+16). B-fragments (W_hh slice) live in 128 VGPRs per lane,
// loaded once. Per step: A-frags (h_{t-1}) read from LLC via relaxed
// agent-scope atomics (sc1, no fences, no L2 maintenance), 32-MFMA K-chain,
// quad-shuffle gate combine, h_t stored via sc1 16-bit atomics.
// Sync: after barrier (which drains each wave's vmcnt), tid0 relaxed-stores
// flag[wid]=t; wave0's 64 lanes poll the 64 flags relaxed, __all(v>=t-1).

__global__ __launch_bounds__(512, 2) void k_lstm(
    const f16* __restrict__ xg, const f16* __restrict__ wr16,
    f16* __restrict__ h_all, unsigned* __restrict__ flags) {
  const unsigned tid = threadIdx.x;
  const unsigned w = tid >> 6, lane = tid & 63;
  const unsigned wid = blockIdx.x;          // 0..63
  const unsigned mt = w >> 2, nt = w & 3;

  const unsigned rl = lane & 15, hi = lane >> 4;
  const unsigned q = rl & 3;                 // gate id within quad
  const unsigned rWl = nt * 16 + rl;         // local W row 0..63
  const unsigned bB = mt * 16 + hi * 4;      // batch base for the 4 acc regs
  const unsigned d = wid * 16 + nt * 4 + (rl >> 2);

  // B-fragments: breg[ks] = wr16[wid*64 + rWl][ks*32 + hi*8 .. +8]  (plain cached)
  f16x8 breg[32];
  {
    const f16* wp = wr16 + (((size_t)wid * 64 + rWl) << 10) + hi * 8;
#pragma unroll
    for (unsigned ks = 0; ks < 32; ++ks) breg[ks] = *(const f16x8*)(wp + ks * 32);
  }

  float c_st[4] = {0.f, 0.f, 0.f, 0.f};

  for (unsigned t = 1; t <= (unsigned)T_; ++t) {
    // x_gates prefetch (independent of h -> issues before the poll)
    float xv[4];
    {
      const f16* xp = xg + ((size_t)(t - 1) * B_ + bB) * G4_ + wid * 64 + rWl;
#pragma unroll
      for (int z = 0; z < 4; ++z) xv[z] = (float)xp[(size_t)z * G4_];
    }
    if (t > 1) {
      if (tid < 64) {
        while (true) {
          unsigned v = __hip_atomic_load(&flags[tid * 32], __ATOMIC_RELAXED,
                                         __HIP_MEMORY_SCOPE_AGENT);
          if (__all((int)(v >= t - 1))) break;
        }
      }
      __syncthreads();
    }
    // gates_partial = h_{t-1}[m-tile] @ Whh_slice[n-tile]^T ; A-frags from LLC
    f32x4 acc = {0.f, 0.f, 0.f, 0.f};
    const f16* hrow = h_all + ((size_t)(t - 1) * B_ + mt * 16 + rl) * H_ + hi * 8;
#pragma unroll
    for (unsigned ks = 0; ks < 32; ++ks) {
      union { u64 u[2]; f16x8 v; } ua;
      ua.u[0] = llc_ld64(hrow + ks * 32);
      ua.u[1] = llc_ld64(hrow + ks * 32 + 4);
      acc = __builtin_amdgcn_mfma_f32_16x16x32_f16(ua.v, breg[ks], acc, 0, 0, 0);
    }
    // activations + state update (each quad holds i,f,g,o of one (d, b-set))
    f16* hw = h_all + ((size_t)t * B_ + bB) * H_ + d;
#pragma unroll
    for (int z = 0; z < 4; ++z) {
      float v = acc[z] + xv[z];
      float a = (q == 2) ? tanhf(v) : 1.0f / (1.0f + __expf(-v));
      float A1 = __shfl_xor(a, 1, 64);
      float A2 = __shfl_xor(a, 2, 64);
      float A3 = __shfl_xor(a, 3, 64);
      float iact = (q == 0) ? a  : (q == 1) ? A1 : (q == 2) ? A2 : A3;
      float fact = (q == 0) ? A1 : (q == 1) ? a  : (q == 2) ? A3 : A2;
      float gact = (q == 0) ? A2 : (q == 1) ? A3 : (q == 2) ? a  : A1;
      float oact = (q == 0) ? A3 : (q == 1) ? A2 : (q == 2) ? A1 : a;
      float cn = fact * c_st[z] + iact * gact;
      c_st[z] = cn;
      float hv = oact * tanhf(cn);
      if (q == 0) {
        f16 hv16 = (f16)hv;
        llc_st16(hw + (size_t)z * H_, __builtin_bit_cast(unsigned short, hv16));
      }
    }
    __syncthreads();   // all waves' sc1 h-stores drained (vmcnt(0) before barrier)
    if (tid == 0) {
      __hip_atomic_store(&flags[wid * 32], t, __ATOMIC_RELAXED,
                         __HIP_MEMORY_SCOPE_AGENT);
    }
  }
}

// ---------------- logits: out[b][t][c] = relu(h[t+1]) . W_score[c] ----------------

__global__ __launch_bounds__(256) void k_logits(
    const f16* __restrict__ h_all, const float* __restrict__ wsc,
    float* __restrict__ out) {
  __shared__ float Ws[2048];
  unsigned tid = threadIdx.x;
  for (unsigned i = tid; i < 512; i += 256) ((float4*)Ws)[i] = ((const float4*)wsc)[i];
  __syncthreads();
  unsigned w = tid >> 6, lane = tid & 63;
  unsigned base = blockIdx.x * 64 + w * 16;
  for (unsigned i = 0; i < 16; ++i) {
    unsigned idx = base + i;                // 0..65535
    unsigned tt = idx >> 5, b = idx & 31;
    const f16* hp = h_all + ((size_t)(idx + 32)) * H_ + lane * 16;
    f16x8 ha = *(const f16x8*)hp;
    f16x8 hb = *(const f16x8*)(hp + 8);
    float s0 = 0.f, s1 = 0.f;
#pragma unroll
    for (int z = 0; z < 8; ++z) {
      float hv = fmaxf((float)ha[z], 0.f);
      s0 += hv * Ws[lane * 16 + z];
      s1 += hv * Ws[1024 + lane * 16 + z];
    }
#pragma unroll
    for (int z = 0; z < 8; ++z) {
      float hv = fmaxf((float)hb[z], 0.f);
      s0 += hv * Ws[lane * 16 + 8 + z];
      s1 += hv * Ws[1024 + lane * 16 + 8 + z];
    }
#pragma unroll
    for (int off = 32; off; off >>= 1) {
      s0 += __shfl_xor(s0, off, 64);
      s1 += __shfl_xor(s1, off, 64);
    }
    if (lane == 0) {
      out[((size_t)b * T_ + tt) * 2 + 0] = s0;
      out[((size_t)b * T_ + tt) * 2 + 1] = s1;
    }
  }
}

// ---------------- launch ----------------

extern "C" void kernel_launch(void* const* d_in, const int* in_sizes, int n_in,
                              void* d_out, int out_size, void* d_ws, size_t ws_size,
                              hipStream_t stream) {
  const int*   seq = (const int*)d_in[0];
  const float* emb = (const float*)d_in[1];
  const float* wih = (const float*)d_in[2];
  const float* whh = (const float*)d_in[3];
  const float* bih = (const float*)d_in[4];
  const float* bhh = (const float*)d_in[5];
  const float* wsc = (const float*)d_in[6];
  float* out = (float*)d_out;
  char* ws = (char*)d_ws;

  const size_t NEED = 790882304ull;
  if (ws_size < NEED) return;  // workspace too small: output stays zero (detectable)

  f16*      emb16 = (f16*)(ws);
  f16*      wih16 = (f16*)(ws + 102926336ull);
  f16*      wr16  = (f16*)(ws + 111314944ull);
  float*    bias  = (float*)(ws + 119703552ull);
  f16*      xg    = (f16*)(ws + 119719936ull);
  f16*      h_all = (f16*)(ws + 656590848ull);
  unsigned* flags = (unsigned*)(ws + 790874112ull);

  hipMemsetAsync(h_all, 0, (size_t)B_ * H_ * 2, stream);      // h_0 = 0
  hipMemsetAsync(flags, 0, 64 * 32 * 4, stream);              // step flags

  k_cvt_f16<<<50257, 256, 0, stream>>>(emb, emb16, 12865792L);
  k_cvt_f16<<<4096, 256, 0, stream>>>(wih, wih16, 1048576L);
  k_whh_reorder<<<2048, 256, 0, stream>>>(whh, wr16);
  k_bias<<<16, 256, 0, stream>>>(bih, bhh, bias);

  k_gemm_xg<<<16384, 256, 0, stream>>>(seq, emb16, wih16, bias, xg);
  k_lstm<<<64, 512, 0, stream>>>(xg, wr16, h_all, flags);
  k_logits<<<1024, 256, 0, stream>>>(h_all, wsc, out);
}